// Round 6
// baseline (8084.367 us; speedup 1.0000x reference)
//
#include <hip/hip_runtime.h>
#include <cstdint>
#include <cstddef>

// ---------------------------------------------------------------------------
// Problem constants
// ---------------------------------------------------------------------------
#define BB 32      // batch
#define TT 512     // seq len
#define DD 512     // emb dim
#define HH 512     // lstm size
#define DIRS 10    // 5 stacks x {fw,bw}
#define LWPITCH 520                      // 512 + 8 pad (16B-aligned rows, 2-way max on b128)
#define SMEM_REC (128 * LWPITCH * 2 + 2 * 2 * 4 * 4 * 64 * 4)   // 133120 + 16384 = 149504
#define HB32SZ ((size_t)3 * DIRS * BB * HH)   // tagged h words, 3 rotating slots

typedef unsigned short u16;
typedef __attribute__((ext_vector_type(8))) short short8;   // 8 x bf16 (4 VGPRs)
typedef __attribute__((ext_vector_type(4))) float f32x4;    // MFMA accum

__device__ __forceinline__ u16 f2b(float f) {
    union { float f; unsigned u; } v; v.f = f;
    unsigned u = v.u;
    u = (u + 0x7FFFu + ((u >> 16) & 1u)) >> 16;   // RNE
    return (u16)u;
}
__device__ __forceinline__ float b2f(u16 b) {
    union { unsigned u; float f; } v; v.u = ((unsigned)b) << 16;
    return v.f;
}
__device__ __forceinline__ float sigm(float x) { return 1.f / (1.f + __expf(-x)); }
__device__ __forceinline__ float tanh_(float x) { return 1.f - 2.f / (1.f + __expf(2.f * x)); }
__device__ __forceinline__ f32x4 fzero() { f32x4 z = {0.f, 0.f, 0.f, 0.f}; return z; }

// pack two tagged-u32 granules (8 words) into one short8 of bf16 payloads
__device__ __forceinline__ short8 pk2(uint4 a, uint4 b) {
    union { unsigned d[4]; short8 s; } u;
    u.d[0] = (a.x & 0xFFFFu) | (a.y << 16);
    u.d[1] = (a.z & 0xFFFFu) | (a.w << 16);
    u.d[2] = (b.x & 0xFFFFu) | (b.y << 16);
    u.d[3] = (b.z & 0xFFFFu) | (b.w << 16);
    return u.s;
}

// ---------------------------------------------------------------------------
// K1: x fp32 -> bf16
// ---------------------------------------------------------------------------
__global__ void k_convx(const float* __restrict__ X, u16* __restrict__ XB) {
    int i = blockIdx.x * 256 + threadIdx.x;
    if (i >= (BB * TT * DD) / 4) return;
    float4 v = ((const float4*)X)[i];
    unsigned lo = (unsigned)f2b(v.x) | ((unsigned)f2b(v.y) << 16);
    unsigned hi = (unsigned)f2b(v.z) | ((unsigned)f2b(v.w) << 16);
    uint2 o; o.x = lo; o.y = hi;
    ((uint2*)XB)[i] = o;
}

// ---------------------------------------------------------------------------
// K2: build WT[d][n][k] = W_src[s][k][n] (bf16), LDS-tiled transpose.
// ---------------------------------------------------------------------------
__global__ void k_wt(const float* __restrict__ Wf, const float* __restrict__ Wb,
                     u16* __restrict__ WT) {
    int d = blockIdx.z, s = d >> 1;
    const float* src = (d & 1) ? Wb : Wf;   // [5][1024][2048]
    __shared__ float tile[32][33];
    int tx = threadIdx.x & 31, ty = threadIdx.x >> 5;
    int kt = blockIdx.x, nt = blockIdx.y;
#pragma unroll
    for (int r = 0; r < 4; r++) {
        int k = kt * 32 + ty + r * 8, n = nt * 32 + tx;
        tile[ty + r * 8][tx] = src[((size_t)s * 1024 + k) * 2048 + n];
    }
    __syncthreads();
#pragma unroll
    for (int r = 0; r < 4; r++) {
        int n = nt * 32 + ty + r * 8, k = kt * 32 + tx;
        WT[((size_t)d * 2048 + n) * 1024 + k] = f2b(tile[tx][ty + r * 8]);
    }
}

// ---------------------------------------------------------------------------
// K3: build head weight WBT[64 c][5120 k] bf16 + bias B64[64].
// ---------------------------------------------------------------------------
__global__ void k_wbt(const float* W1, const float* W2, const float* W3, const float* W4,
                      const float* b1, const float* b2, const float* b3, const float* b4,
                      u16* __restrict__ WBT, float* __restrict__ B64) {
    int idx = blockIdx.x * 256 + threadIdx.x;
    const int off[4] = {0, 17, 26, 51};
    const int tg[4]  = {17, 9, 25, 13};
    if (idx < 64) {
        int c = idx;
        int ti = (c < 17) ? 0 : (c < 26) ? 1 : (c < 51) ? 2 : 3;
        const float* bbp[4] = {b1, b2, b3, b4};
        B64[c] = bbp[ti][c - off[ti]];
    }
    if (idx >= 64 * 5120) return;
    int c = idx / 5120, k = idx % 5120;
    int ti = (c < 17) ? 0 : (c < 26) ? 1 : (c < 51) ? 2 : 3;
    const float* Ws[4] = {W1, W2, W3, W4};
    int tag = c - off[ti];
    float v;
    if (k < 4096) {
        int i = k >> 10, kk = k & 1023;
        v = (i == ti) ? Ws[ti][(size_t)kk * tg[ti] + tag] : 0.f;
    } else {
        int kk = k - 4096;
        v = Ws[ti][(size_t)(1024 + kk) * tg[ti] + tag];
    }
    WBT[(size_t)c * 5120 + k] = f2b(v);
}

// ---------------------------------------------------------------------------
// K5: persistent kernel, ROUND-0 GEOMETRY (16 blocks/dir) + TAG-IN-DATA
//   h exchange (round-11/12; round-5 submission was never run — infra):
//   - h stored as u32 = (tag<<16)|bf16, tag = t+1, in a 3-slot rotating
//     buffer Hb32[slot][d][b][u], slot = step % 3.
//   - NO flags, NO publish, NO producer drain on the critical path: the
//     consumer's poll load IS the data load. Chain = store-landing + poll
//     read (~2 LLC RTTs) vs 4 RTTs for the flag protocol.
//   - 3 slots are REQUIRED: a writer clobbers slot t%3 only at the end of
//     step t+2, after poll(t+2) proved every block finished step t+1 and
//     is therefore done reading slot t%3. With 2 slots a writer clobbers
//     the slot a 1-iter-behind block still reads.
//   - per-word tags make partial arrival safe (tag+payload in one dword).
//   - the poll is ONE asm block: 16 dwordx4 + internal vmcnt(0), so its
//     outputs are truly ready at asm exit (no spill-in-flight hazard —
//     round-3 lesson).
// ---------------------------------------------------------------------------
__global__ __launch_bounds__(512, 2) void k_rec(
    const u16* __restrict__ WT, const u16* __restrict__ XB,
    const float* __restrict__ bfw, const float* __restrict__ bbw,
    unsigned* __restrict__ Hb32, u16* __restrict__ OUTS,
    const int* __restrict__ lens)
{
    extern __shared__ char smem[];
    u16* lWx = (u16*)smem;                             // [128][LWPITCH] bf16
    float* red = (float*)(smem + 128 * LWPITCH * 2);   // [2][2][4][4][64]

    int blk = blockIdx.x, d = blk >> 4, jj = blk & 15;
    int s = d >> 1, isbw = d & 1;
    int tid = threadIdx.x, w = tid >> 6, lane = tid & 63, quad = lane >> 4, l15 = lane & 15;
    int mtile = w & 1, nhalf = (w >> 1) & 1, khalf = w >> 2;

    // ---- stage W_x slice into LDS (once) ----
#pragma unroll
    for (int it = 0; it < 16; ++it) {
        int g16 = it * 512 + tid;          // 8192 granules of 16B
        int row = g16 >> 6, c = g16 & 63;
        int n = (row >> 5) * 512 + jj * 32 + (row & 31);
        const u16* src = WT + ((size_t)d * 2048 + n) * 1024 + c * 8;   // x half: k in [0,512)
        *(uint4*)(lWx + row * LWPITCH + c * 8) = *(const uint4*)src;
    }

    // ---- W_h fragments: persistent registers/AGPRs ----
    short8 Bf[8][4];
#pragma unroll
    for (int ks = 0; ks < 8; ks++) {
        int k0 = khalf * 256 + ks * 32;
#pragma unroll
        for (int g = 0; g < 4; g++) {
            int n = g * 512 + jj * 32 + nhalf * 16 + l15;
            Bf[ks][g] = *(const short8*)(WT + ((size_t)d * 2048 + n) * 1024 + 512 + k0 + quad * 8);
        }
    }

    // ---- per-lane persistent state ----
    int bA = mtile * 16 + l15;             // A-fragment row (batch index)
    int lbA = lens[bA];
    int ug = jj * 32 + nhalf * 16 + l15;   // global unit index (epilogue lanes)
    const float* bias = (isbw ? bbw : bfw) + (size_t)s * 2048;
    float c_reg[4], hprev[4], bv_r[4];
    int lb_r[4];
    if (khalf == 0) {
#pragma unroll
        for (int g = 0; g < 4; g++) bv_r[g] = bias[g * 512 + ug];
#pragma unroll
        for (int r = 0; r < 4; r++) {
            int b = mtile * 16 + quad * 4 + r;
            lb_r[r] = lens[b];
            c_reg[r] = 0.f;
            hprev[r] = 0.f;
        }
    }
    __syncthreads();   // lWx ready

    for (int t = 0; t < TT; ++t) {
        // ---- x loads (plain, compiler-tracked; in flight during the poll) ----
        int srcT = isbw ? ((t < lbA) ? (lbA - 1 - t) : t) : t;
        const u16* xrow = XB + ((size_t)bA * TT + srcT) * DD + khalf * 256;
        uint4 xraw[8];
#pragma unroll
        for (int ks = 0; ks < 8; ks++)
            xraw[ks] = *(const uint4*)(xrow + ks * 32 + quad * 8);

        // ---- tag-in-data poll: 16 coherent dwordx4 = this wave's k-half ----
        int sl = t % 3;
        const unsigned* hb = Hb32 + (((size_t)sl * DIRS + d) * BB + bA) * HH
                             + khalf * 256 + quad * 8;
        unsigned exp_ = ((unsigned)t) << 16;
        uint4 p0, p1, p2, p3, p4, p5, p6, p7, p8, p9, pA, pB, pC, pD, pE, pF;
        for (int spin = 0; spin < (1 << 16); ++spin) {
            asm volatile(
                "global_load_dwordx4 %0, %16, off sc0 sc1\n\t"
                "global_load_dwordx4 %1, %16, off offset:16 sc0 sc1\n\t"
                "global_load_dwordx4 %2, %16, off offset:128 sc0 sc1\n\t"
                "global_load_dwordx4 %3, %16, off offset:144 sc0 sc1\n\t"
                "global_load_dwordx4 %4, %16, off offset:256 sc0 sc1\n\t"
                "global_load_dwordx4 %5, %16, off offset:272 sc0 sc1\n\t"
                "global_load_dwordx4 %6, %16, off offset:384 sc0 sc1\n\t"
                "global_load_dwordx4 %7, %16, off offset:400 sc0 sc1\n\t"
                "global_load_dwordx4 %8, %16, off offset:512 sc0 sc1\n\t"
                "global_load_dwordx4 %9, %16, off offset:528 sc0 sc1\n\t"
                "global_load_dwordx4 %10, %16, off offset:640 sc0 sc1\n\t"
                "global_load_dwordx4 %11, %16, off offset:656 sc0 sc1\n\t"
                "global_load_dwordx4 %12, %16, off offset:768 sc0 sc1\n\t"
                "global_load_dwordx4 %13, %16, off offset:784 sc0 sc1\n\t"
                "global_load_dwordx4 %14, %16, off offset:896 sc0 sc1\n\t"
                "global_load_dwordx4 %15, %16, off offset:912 sc0 sc1\n\t"
                "s_waitcnt vmcnt(0)"
                : "=&v"(p0), "=&v"(p1), "=&v"(p2), "=&v"(p3),
                  "=&v"(p4), "=&v"(p5), "=&v"(p6), "=&v"(p7),
                  "=&v"(p8), "=&v"(p9), "=&v"(pA), "=&v"(pB),
                  "=&v"(pC), "=&v"(pD), "=&v"(pE), "=&v"(pF)
                : "v"(hb) : "memory");
            // all 64 tags must equal t: OR of (word ^ (t<<16)) has hi16 == 0
#define TB_(P) ((P.x ^ exp_) | (P.y ^ exp_) | (P.z ^ exp_) | (P.w ^ exp_))
            unsigned bad = TB_(p0) | TB_(p1) | TB_(p2) | TB_(p3)
                         | TB_(p4) | TB_(p5) | TB_(p6) | TB_(p7)
                         | TB_(p8) | TB_(p9) | TB_(pA) | TB_(pB)
                         | TB_(pC) | TB_(pD) | TB_(pE) | TB_(pF);
#undef TB_
            if (__all((int)((bad >> 16) == 0u))) break;
            __builtin_amdgcn_s_sleep(1);
        }

        // ---- repack payloads to bf16 A-fragments ----
        short8 Af[8];
        Af[0] = pk2(p0, p1); Af[1] = pk2(p2, p3);
        Af[2] = pk2(p4, p5); Af[3] = pk2(p6, p7);
        Af[4] = pk2(p8, p9); Af[5] = pk2(pA, pB);
        Af[6] = pk2(pC, pD); Af[7] = pk2(pE, pF);

        f32x4 acc[4];
#pragma unroll
        for (int g = 0; g < 4; g++) acc[g] = fzero();

        // ---- x-GEMM from LDS weights ----
#pragma unroll
        for (int ks = 0; ks < 8; ks++) {
            short8 a = *(const short8*)(&xraw[ks]);
#pragma unroll
            for (int g = 0; g < 4; g++) {
                short8 bfr = *(const short8*)(lWx + (g * 32 + nhalf * 16 + l15) * LWPITCH
                                              + khalf * 256 + ks * 32 + quad * 8);
                acc[g] = __builtin_amdgcn_mfma_f32_16x16x32_bf16(a, bfr, acc[g], 0, 0, 0);
            }
        }
        // ---- h-GEMM from polled fragments ----
#pragma unroll
        for (int ks = 0; ks < 8; ks++) {
#pragma unroll
            for (int g = 0; g < 4; g++)
                acc[g] = __builtin_amdgcn_mfma_f32_16x16x32_bf16(Af[ks], Bf[ks][g], acc[g], 0, 0, 0);
        }

        if (khalf == 1) {
#pragma unroll
            for (int g = 0; g < 4; g++)
#pragma unroll
                for (int r = 0; r < 4; r++)
                    red[((((size_t)mtile * 2 + nhalf) * 4 + g) * 4 + r) * 64 + lane] = acc[g][r];
        }
        __syncthreads();
        if (khalf == 0) {
#pragma unroll
            for (int g = 0; g < 4; g++)
#pragma unroll
                for (int r = 0; r < 4; r++)
                    acc[g][r] += red[((((size_t)mtile * 2 + nhalf) * 4 + g) * 4 + r) * 64 + lane];

            unsigned tg1 = ((unsigned)(t + 1)) << 16;
            int sl1 = (t + 1) % 3;
            unsigned* hout = Hb32 + ((size_t)sl1 * DIRS + d) * BB * HH;
#pragma unroll
            for (int r = 0; r < 4; r++) {
                int b = mtile * 16 + quad * 4 + r;
                int lb = lb_r[r];
                float zi = acc[0][r] + bv_r[0];
                float zj = acc[1][r] + bv_r[1];
                float zf = acc[2][r] + bv_r[2];
                float zo = acc[3][r] + bv_r[3];
                float cn = sigm(zf + 1.f) * c_reg[r] + sigm(zi) * tanh_(zj);
                float hn = sigm(zo) * tanh_(cn);
                bool act = t < lb;
                if (act) c_reg[r] = cn;
                u16 hv = f2b(act ? hn : hprev[r]);
                hprev[r] = b2f(hv);
                // tagged store: publication IS the data
                __hip_atomic_store(&hout[(size_t)b * HH + ug], tg1 | (unsigned)hv,
                                   __ATOMIC_RELAXED, __HIP_MEMORY_SCOPE_AGENT);
                int twr = isbw ? (act ? (lb - 1 - t) : t) : t;   // fused reverse scatter
                OUTS[(((size_t)s * BB + b) * TT + twr) * 1024 + isbw * 512 + ug] = f2b(act ? hn : 0.f);
            }
        }
        __syncthreads();   // protect red for next iteration
    }
}

// ---------------------------------------------------------------------------
// K6: heads. logits[16384, 64] = U[16384, 5120] @ WBT^T + B64.
// ---------------------------------------------------------------------------
__global__ __launch_bounds__(256) void k_head(
    const u16* __restrict__ OUTS, const u16* __restrict__ WBT,
    const float* __restrict__ B64, float* __restrict__ OUT)
{
    int tid = threadIdx.x, w = tid >> 6, lane = tid & 63, quad = lane >> 4, l15 = lane & 15;
    int mtile = blockIdx.x * 4 + w, r0 = mtile * 16;
    int row_a = r0 + l15, ba = row_a >> 9, ta = row_a & 511;
    f32x4 acc[4];
#pragma unroll
    for (int ni = 0; ni < 4; ni++) acc[ni] = fzero();

    for (int k0 = 0; k0 < 5120; k0 += 32) {
        int kidx = k0 + quad * 8;
        int blkk = kidx >> 10, kk = kidx & 1023;
        short8 a = *(const short8*)(OUTS + (((size_t)blkk * BB + ba) * TT + ta) * 1024 + kk);
#pragma unroll
        for (int ni = 0; ni < 4; ni++) {
            short8 bf = *(const short8*)(WBT + (size_t)(ni * 16 + l15) * 5120 + kidx);
            acc[ni] = __builtin_amdgcn_mfma_f32_16x16x32_bf16(a, bf, acc[ni], 0, 0, 0);
        }
    }
#pragma unroll
    for (int ni = 0; ni < 4; ni++) {
        int c = ni * 16 + l15;
        float bv = B64[c];
#pragma unroll
        for (int r = 0; r < 4; r++) {
            int row = r0 + quad * 4 + r;
            OUT[(size_t)row * 64 + c] = acc[ni][r] + bv;
        }
    }
}

// ---------------------------------------------------------------------------
extern "C" void kernel_launch(void* const* d_in, const int* in_sizes, int n_in,
                              void* d_out, int out_size, void* d_ws, size_t ws_size,
                              hipStream_t stream) {
    const float* X   = (const float*)d_in[0];
    const int* lens  = (const int*)d_in[1];
    const float* Wf  = (const float*)d_in[2];
    const float* bf_ = (const float*)d_in[3];
    const float* Wb  = (const float*)d_in[4];
    const float* bb_ = (const float*)d_in[5];
    const float* W1  = (const float*)d_in[6];
    const float* b1  = (const float*)d_in[7];
    const float* W2  = (const float*)d_in[8];
    const float* b2  = (const float*)d_in[9];
    const float* W3  = (const float*)d_in[10];
    const float* b3  = (const float*)d_in[11];
    const float* W4  = (const float*)d_in[12];
    const float* b4  = (const float*)d_in[13];

    // ---- runtime workspace layout ----
    char* ws = (char*)d_ws;
    size_t off = 0;
    auto take = [&](size_t bytes) { size_t o = off; off += (bytes + 255) & ~(size_t)255; return o; };
    size_t wtOff   = take((size_t)DIRS * 2048 * 1024 * 2);
    size_t xbOff   = take((size_t)BB * TT * DD * 2);
    size_t outsOff = take((size_t)5 * BB * TT * 1024 * 2);
    size_t hbOff   = take(HB32SZ * 4);                 // 3-slot tagged h (1.92 MB)
    size_t wbtOff  = take((size_t)64 * 5120 * 2);
    size_t b64Off  = take((size_t)64 * 4);

    u16* WT    = (u16*)(ws + wtOff);
    u16* XB    = (u16*)(ws + xbOff);
    u16* OUTS  = (u16*)(ws + outsOff);
    unsigned* HB32 = (unsigned*)(ws + hbOff);
    u16* WBT   = (u16*)(ws + wbtOff);
    float* B64 = (float*)(ws + b64Off);

    // zero ALL h slots every launch: tag 0 == "ready for t=0", payload 0;
    // stale tags from a previous graph replay MUST be cleared.
    hipMemsetAsync(ws + hbOff, 0, HB32SZ * 4, stream);

    // 149.5 KB dynamic LDS for the persistent kernel
    (void)hipFuncSetAttribute((const void*)k_rec,
                              hipFuncAttributeMaxDynamicSharedMemorySize, SMEM_REC);

    k_convx<<<8192, 256, 0, stream>>>(X, XB);
    k_wt<<<dim3(32, 64, 10), 256, 0, stream>>>(Wf, Wb, WT);
    k_wbt<<<1280, 256, 0, stream>>>(W1, W2, W3, W4, b1, b2, b3, b4, WBT, B64);

    // one persistent dispatch for all 512 timesteps (round-0 geometry)
    k_rec<<<160, 512, SMEM_REC, stream>>>(WT, XB, bf_, bb_, HB32, OUTS, lens);

    k_head<<<256, 256, 0, stream>>>(OUTS, WBT, B64, (float*)d_out);
}

// Round 7
// 3125.258 us; speedup vs baseline: 2.5868x; 2.5868x over previous
//
#include <hip/hip_runtime.h>
#include <cstdint>
#include <cstddef>

// ---------------------------------------------------------------------------
// Problem constants
// ---------------------------------------------------------------------------
#define BB 32      // batch
#define TT 512     // seq len
#define DD 512     // emb dim
#define HH 512     // lstm size
#define DIRS 10    // 5 stacks x {fw,bw}
#define HSZ ((size_t)DIRS * BB * HH)     // elems per h ping-pong buffer
#define LWPITCH 520                      // 512 + 8 pad (16B-aligned rows, 2-way max on b128)
#define SMEM_REC (128 * LWPITCH * 2 + 2 * 2 * 4 * 4 * 64 * 4)   // 133120 + 16384 = 149504

typedef unsigned short u16;
typedef __attribute__((ext_vector_type(8))) short short8;   // 8 x bf16 (4 VGPRs)
typedef __attribute__((ext_vector_type(4))) float f32x4;    // MFMA accum

__device__ __forceinline__ u16 f2b(float f) {
    union { float f; unsigned u; } v; v.f = f;
    unsigned u = v.u;
    u = (u + 0x7FFFu + ((u >> 16) & 1u)) >> 16;   // RNE
    return (u16)u;
}
__device__ __forceinline__ float b2f(u16 b) {
    union { unsigned u; float f; } v; v.u = ((unsigned)b) << 16;
    return v.f;
}
__device__ __forceinline__ float sigm(float x) { return 1.f / (1.f + __expf(-x)); }
__device__ __forceinline__ float tanh_(float x) { return 1.f - 2.f / (1.f + __expf(2.f * x)); }
__device__ __forceinline__ f32x4 fzero() { f32x4 z = {0.f, 0.f, 0.f, 0.f}; return z; }

// Coherent 16B load (LLC, vmcnt-tracked). DISCIPLINE (round-3/4 lesson):
// results are compiler-invisible in-flight values — issue -> explicit
// s_waitcnt vmcnt(0)+sched_barrier -> consume, all inside one phase;
// never live across a __syncthreads.
__device__ __forceinline__ uint4 load_coh16(const u16* p) {
    uint4 r;
    asm volatile("global_load_dwordx4 %0, %1, off sc0 sc1"
                 : "=v"(r) : "v"(p) : "memory");
    return r;
}

// ---------------------------------------------------------------------------
// K1: x fp32 -> bf16
// ---------------------------------------------------------------------------
__global__ void k_convx(const float* __restrict__ X, u16* __restrict__ XB) {
    int i = blockIdx.x * 256 + threadIdx.x;
    if (i >= (BB * TT * DD) / 4) return;
    float4 v = ((const float4*)X)[i];
    unsigned lo = (unsigned)f2b(v.x) | ((unsigned)f2b(v.y) << 16);
    unsigned hi = (unsigned)f2b(v.z) | ((unsigned)f2b(v.w) << 16);
    uint2 o; o.x = lo; o.y = hi;
    ((uint2*)XB)[i] = o;
}

// ---------------------------------------------------------------------------
// K2: build WT[d][n][k] = W_src[s][k][n] (bf16), LDS-tiled transpose.
// ---------------------------------------------------------------------------
__global__ void k_wt(const float* __restrict__ Wf, const float* __restrict__ Wb,
                     u16* __restrict__ WT) {
    int d = blockIdx.z, s = d >> 1;
    const float* src = (d & 1) ? Wb : Wf;   // [5][1024][2048]
    __shared__ float tile[32][33];
    int tx = threadIdx.x & 31, ty = threadIdx.x >> 5;
    int kt = blockIdx.x, nt = blockIdx.y;
#pragma unroll
    for (int r = 0; r < 4; r++) {
        int k = kt * 32 + ty + r * 8, n = nt * 32 + tx;
        tile[ty + r * 8][tx] = src[((size_t)s * 1024 + k) * 2048 + n];
    }
    __syncthreads();
#pragma unroll
    for (int r = 0; r < 4; r++) {
        int n = nt * 32 + ty + r * 8, k = kt * 32 + tx;
        WT[((size_t)d * 2048 + n) * 1024 + k] = f2b(tile[tx][ty + r * 8]);
    }
}

// ---------------------------------------------------------------------------
// K3: build head weight WBT[64 c][5120 k] bf16 + bias B64[64].
// ---------------------------------------------------------------------------
__global__ void k_wbt(const float* W1, const float* W2, const float* W3, const float* W4,
                      const float* b1, const float* b2, const float* b3, const float* b4,
                      u16* __restrict__ WBT, float* __restrict__ B64) {
    int idx = blockIdx.x * 256 + threadIdx.x;
    const int off[4] = {0, 17, 26, 51};
    const int tg[4]  = {17, 9, 25, 13};
    if (idx < 64) {
        int c = idx;
        int ti = (c < 17) ? 0 : (c < 26) ? 1 : (c < 51) ? 2 : 3;
        const float* bbp[4] = {b1, b2, b3, b4};
        B64[c] = bbp[ti][c - off[ti]];
    }
    if (idx >= 64 * 5120) return;
    int c = idx / 5120, k = idx % 5120;
    int ti = (c < 17) ? 0 : (c < 26) ? 1 : (c < 51) ? 2 : 3;
    const float* Ws[4] = {W1, W2, W3, W4};
    int tag = c - off[ti];
    float v;
    if (k < 4096) {
        int i = k >> 10, kk = k & 1023;
        v = (i == ti) ? Ws[ti][(size_t)kk * tg[ti] + tag] : 0.f;
    } else {
        int kk = k - 4096;
        v = Ws[ti][(size_t)(1024 + kk) * tg[ti] + tag];
    }
    WBT[(size_t)c * 5120 + k] = f2b(v);
}

// ---------------------------------------------------------------------------
// K5: persistent kernel — ROUND-0 GEOMETRY + de-serialized handoff (r13):
//   - publish: per-block flag word flg[d*16+jj] = t+1 (tid0, relaxed agent
//     store AFTER the store-draining barrier). No RMW chain.
//   - poll: EVERY wave reads the dir's 16-word (64B) flag line (lane<16,
//     compiler-visible atomic loads) and proceeds the moment all >= t.
//     No release barrier, no single-poller park. 2 barriers/step (was 3).
//   - wait window filled: x-GEMM ks0..5 runs BEFORE the poll (x has no h
//     dependency); after poll, h loads issue and ks6..7 hide part of the
//     RTT; explicit vmcnt(0) fence; h-GEMM.
//   - narrow poll only (64B/line/attempt) — round-6 counters proved wide
//     polls multiply fabric traffic 5x.
//   Safety: poll passing t proves all blocks finished step t-1, hence done
//   reading buf (t-1)&1 == (t+1)&1 before anyone stores h(t+1) there (same
//   2-buffer invariant round 0 relied on). Flags are monotone; stale
//   own-flag just means a short extra spin.
// ---------------------------------------------------------------------------
__global__ __launch_bounds__(512, 2) void k_rec(
    const u16* __restrict__ WT, const u16* __restrict__ XB,
    const float* __restrict__ bfw, const float* __restrict__ bbw,
    u16* __restrict__ Hbuf, u16* __restrict__ OUTS,
    const int* __restrict__ lens, unsigned* __restrict__ flg)
{
    extern __shared__ char smem[];
    u16* lWx = (u16*)smem;                             // [128][LWPITCH] bf16
    float* red = (float*)(smem + 128 * LWPITCH * 2);   // [2][2][4][4][64]

    int blk = blockIdx.x, d = blk >> 4, jj = blk & 15;
    int s = d >> 1, isbw = d & 1;
    int tid = threadIdx.x, w = tid >> 6, lane = tid & 63, quad = lane >> 4, l15 = lane & 15;
    int mtile = w & 1, nhalf = (w >> 1) & 1, khalf = w >> 2;

    // ---- stage W_x slice into LDS (once) ----
#pragma unroll
    for (int it = 0; it < 16; ++it) {
        int g16 = it * 512 + tid;          // 8192 granules of 16B
        int row = g16 >> 6, c = g16 & 63;
        int n = (row >> 5) * 512 + jj * 32 + (row & 31);
        const u16* src = WT + ((size_t)d * 2048 + n) * 1024 + c * 8;   // x half: k in [0,512)
        *(uint4*)(lWx + row * LWPITCH + c * 8) = *(const uint4*)src;
    }

    // ---- W_h fragments: persistent registers/AGPRs ----
    short8 Bf[8][4];
#pragma unroll
    for (int ks = 0; ks < 8; ks++) {
        int k0 = khalf * 256 + ks * 32;
#pragma unroll
        for (int g = 0; g < 4; g++) {
            int n = g * 512 + jj * 32 + nhalf * 16 + l15;
            Bf[ks][g] = *(const short8*)(WT + ((size_t)d * 2048 + n) * 1024 + 512 + k0 + quad * 8);
        }
    }

    // ---- per-lane persistent state ----
    int bA = mtile * 16 + l15;             // A-fragment row (batch index)
    int lbA = lens[bA];
    int ug = jj * 32 + nhalf * 16 + l15;   // global unit index (epilogue lanes)
    const float* bias = (isbw ? bbw : bfw) + (size_t)s * 2048;
    float c_reg[4], hprev[4], bv_r[4];
    int lb_r[4];
    if (khalf == 0) {
#pragma unroll
        for (int g = 0; g < 4; g++) bv_r[g] = bias[g * 512 + ug];
#pragma unroll
        for (int r = 0; r < 4; r++) {
            int b = mtile * 16 + quad * 4 + r;
            lb_r[r] = lens[b];
            c_reg[r] = 0.f;
            hprev[r] = 0.f;
        }
    }
    const unsigned* fline = flg + d * 16;
    __syncthreads();   // lWx ready

    for (int t = 0; t < TT; ++t) {
        // ---- x loads (plain, compiler-tracked) ----
        int srcT = isbw ? ((t < lbA) ? (lbA - 1 - t) : t) : t;
        const u16* xrow = XB + ((size_t)bA * TT + srcT) * DD + khalf * 256;
        uint4 xraw[8];
#pragma unroll
        for (int ks = 0; ks < 8; ks++)
            xraw[ks] = *(const uint4*)(xrow + ks * 32 + quad * 8);

        f32x4 acc[4];
#pragma unroll
        for (int g = 0; g < 4; g++) acc[g] = fzero();

        // ---- x-GEMM ks0..5 BEFORE the poll: fills the publish/straggler
        //      window with h-independent compute ----
#pragma unroll
        for (int ks = 0; ks < 6; ks++) {
            short8 a = *(const short8*)(&xraw[ks]);
#pragma unroll
            for (int g = 0; g < 4; g++) {
                short8 bfr = *(const short8*)(lWx + (g * 32 + nhalf * 16 + l15) * LWPITCH
                                              + khalf * 256 + ks * 32 + quad * 8);
                acc[g] = __builtin_amdgcn_mfma_f32_16x16x32_bf16(a, bfr, acc[g], 0, 0, 0);
            }
        }

        // ---- per-wave narrow poll: 64B flag line, all 16 blocks >= t ----
        {
            unsigned tgt = (unsigned)t;
            unsigned f = tgt;
            if (lane < 16)
                f = __hip_atomic_load(fline + lane, __ATOMIC_RELAXED,
                                      __HIP_MEMORY_SCOPE_AGENT);
            int spin = 0;
            while (!__all((int)(f >= tgt)) && spin < (1 << 22)) {
                __builtin_amdgcn_s_sleep(1);
                f = tgt;
                if (lane < 16)
                    f = __hip_atomic_load(fline + lane, __ATOMIC_RELAXED,
                                          __HIP_MEMORY_SCOPE_AGENT);
                ++spin;
            }
        }

        // ---- h loads (coh asm), issued immediately after poll ----
        const u16* hin = Hbuf + (size_t)(t & 1) * HSZ + (size_t)d * BB * HH;
        uint4 araw[8];
#pragma unroll
        for (int ks = 0; ks < 8; ks++)
            araw[ks] = load_coh16(hin + (size_t)bA * HH + khalf * 256 + ks * 32 + quad * 8);

        // ---- x-GEMM ks6..7: hides part of the h-load RTT ----
#pragma unroll
        for (int ks = 6; ks < 8; ks++) {
            short8 a = *(const short8*)(&xraw[ks]);
#pragma unroll
            for (int g = 0; g < 4; g++) {
                short8 bfr = *(const short8*)(lWx + (g * 32 + nhalf * 16 + l15) * LWPITCH
                                              + khalf * 256 + ks * 32 + quad * 8);
                acc[g] = __builtin_amdgcn_mfma_f32_16x16x32_bf16(a, bfr, acc[g], 0, 0, 0);
            }
        }

        // drain asm h loads, then h-GEMM (rule #18 fence)
        asm volatile("s_waitcnt vmcnt(0)" ::: "memory");
        __builtin_amdgcn_sched_barrier(0);
#pragma unroll
        for (int ks = 0; ks < 8; ks++) {
            short8 a = *(const short8*)(&araw[ks]);
#pragma unroll
            for (int g = 0; g < 4; g++)
                acc[g] = __builtin_amdgcn_mfma_f32_16x16x32_bf16(a, Bf[ks][g], acc[g], 0, 0, 0);
        }

        // ---- khalf exchange through LDS ----
        if (khalf == 1) {
#pragma unroll
            for (int g = 0; g < 4; g++)
#pragma unroll
                for (int r = 0; r < 4; r++)
                    red[((((size_t)mtile * 2 + nhalf) * 4 + g) * 4 + r) * 64 + lane] = acc[g][r];
        }
        __syncthreads();   // barrier #1: red ready
        if (khalf == 0) {
#pragma unroll
            for (int g = 0; g < 4; g++)
#pragma unroll
                for (int r = 0; r < 4; r++)
                    acc[g][r] += red[((((size_t)mtile * 2 + nhalf) * 4 + g) * 4 + r) * 64 + lane];

            u16* hout = Hbuf + (size_t)((t + 1) & 1) * HSZ + (size_t)d * BB * HH;
#pragma unroll
            for (int r = 0; r < 4; r++) {
                int b = mtile * 16 + quad * 4 + r;
                int lb = lb_r[r];
                float zi = acc[0][r] + bv_r[0];
                float zj = acc[1][r] + bv_r[1];
                float zf = acc[2][r] + bv_r[2];
                float zo = acc[3][r] + bv_r[3];
                float cn = sigm(zf + 1.f) * c_reg[r] + sigm(zi) * tanh_(zj);
                float hn = sigm(zo) * tanh_(cn);
                bool act = t < lb;
                if (act) c_reg[r] = cn;
                u16 hv = f2b(act ? hn : hprev[r]);
                hprev[r] = b2f(hv);
                __hip_atomic_store(&hout[(size_t)b * HH + ug], hv,
                                   __ATOMIC_RELAXED, __HIP_MEMORY_SCOPE_AGENT);
                int twr = isbw ? (act ? (lb - 1 - t) : t) : t;   // fused reverse scatter
                OUTS[(((size_t)s * BB + b) * TT + twr) * 1024 + isbw * 512 + ug] = f2b(act ? hn : 0.f);
            }
        }
        __syncthreads();   // barrier #2: drains h/OUTS stores on all waves,
                           // doubles as red-protect for next iteration
        if (tid == 0)
            __hip_atomic_store(flg + d * 16 + jj, (unsigned)(t + 1),
                               __ATOMIC_RELAXED, __HIP_MEMORY_SCOPE_AGENT);
    }
}

// ---------------------------------------------------------------------------
// K6: heads. logits[16384, 64] = U[16384, 5120] @ WBT^T + B64.
// ---------------------------------------------------------------------------
__global__ __launch_bounds__(256) void k_head(
    const u16* __restrict__ OUTS, const u16* __restrict__ WBT,
    const float* __restrict__ B64, float* __restrict__ OUT)
{
    int tid = threadIdx.x, w = tid >> 6, lane = tid & 63, quad = lane >> 4, l15 = lane & 15;
    int mtile = blockIdx.x * 4 + w, r0 = mtile * 16;
    int row_a = r0 + l15, ba = row_a >> 9, ta = row_a & 511;
    f32x4 acc[4];
#pragma unroll
    for (int ni = 0; ni < 4; ni++) acc[ni] = fzero();

    for (int k0 = 0; k0 < 5120; k0 += 32) {
        int kidx = k0 + quad * 8;
        int blkk = kidx >> 10, kk = kidx & 1023;
        short8 a = *(const short8*)(OUTS + (((size_t)blkk * BB + ba) * TT + ta) * 1024 + kk);
#pragma unroll
        for (int ni = 0; ni < 4; ni++) {
            short8 bf = *(const short8*)(WBT + (size_t)(ni * 16 + l15) * 5120 + kidx);
            acc[ni] = __builtin_amdgcn_mfma_f32_16x16x32_bf16(a, bf, acc[ni], 0, 0, 0);
        }
    }
#pragma unroll
    for (int ni = 0; ni < 4; ni++) {
        int c = ni * 16 + l15;
        float bv = B64[c];
#pragma unroll
        for (int r = 0; r < 4; r++) {
            int row = r0 + quad * 4 + r;
            OUT[(size_t)row * 64 + c] = acc[ni][r] + bv;
        }
    }
}

// ---------------------------------------------------------------------------
extern "C" void kernel_launch(void* const* d_in, const int* in_sizes, int n_in,
                              void* d_out, int out_size, void* d_ws, size_t ws_size,
                              hipStream_t stream) {
    const float* X   = (const float*)d_in[0];
    const int* lens  = (const int*)d_in[1];
    const float* Wf  = (const float*)d_in[2];
    const float* bf_ = (const float*)d_in[3];
    const float* Wb  = (const float*)d_in[4];
    const float* bb_ = (const float*)d_in[5];
    const float* W1  = (const float*)d_in[6];
    const float* b1  = (const float*)d_in[7];
    const float* W2  = (const float*)d_in[8];
    const float* b2  = (const float*)d_in[9];
    const float* W3  = (const float*)d_in[10];
    const float* b3  = (const float*)d_in[11];
    const float* W4  = (const float*)d_in[12];
    const float* b4  = (const float*)d_in[13];

    // ---- runtime workspace layout ----
    char* ws = (char*)d_ws;
    size_t off = 0;
    auto take = [&](size_t bytes) { size_t o = off; off += (bytes + 255) & ~(size_t)255; return o; };
    size_t wtOff   = take((size_t)DIRS * 2048 * 1024 * 2);
    size_t xbOff   = take((size_t)BB * TT * DD * 2);
    size_t outsOff = take((size_t)5 * BB * TT * 1024 * 2);
    size_t hOff    = take((size_t)2 * HSZ * 2);
    size_t flgOff  = take((size_t)DIRS * 16 * 4);      // 16 flag words (64B line) per dir
    size_t wbtOff  = take((size_t)64 * 5120 * 2);
    size_t b64Off  = take((size_t)64 * 4);

    u16* WT    = (u16*)(ws + wtOff);
    u16* XB    = (u16*)(ws + xbOff);
    u16* OUTS  = (u16*)(ws + outsOff);
    u16* Hbuf  = (u16*)(ws + hOff);
    unsigned* FLG = (unsigned*)(ws + flgOff);
    u16* WBT   = (u16*)(ws + wbtOff);
    float* B64 = (float*)(ws + b64Off);

    // zero the ENTIRE [H | FLG] span every launch (flags MUST reset; h(0)=0)
    hipMemsetAsync(ws + hOff, 0, wbtOff - hOff, stream);

    // 149.5 KB dynamic LDS for the persistent kernel
    (void)hipFuncSetAttribute((const void*)k_rec,
                              hipFuncAttributeMaxDynamicSharedMemorySize, SMEM_REC);

    k_convx<<<8192, 256, 0, stream>>>(X, XB);
    k_wt<<<dim3(32, 64, 10), 256, 0, stream>>>(Wf, Wb, WT);
    k_wbt<<<1280, 256, 0, stream>>>(W1, W2, W3, W4, b1, b2, b3, b4, WBT, B64);

    // one persistent dispatch for all 512 timesteps (round-0 geometry)
    k_rec<<<160, 512, SMEM_REC, stream>>>(WT, XB, bf_, bb_, Hbuf, OUTS, lens, FLG);

    k_head<<<256, 256, 0, stream>>>(OUTS, WBT, B64, (float*)d_out);
}